// Round 3
// baseline (202.860 us; speedup 1.0000x reference)
//
#include <hip/hip_runtime.h>
#include <hip/hip_bf16.h>

#define W512   512
#define PATCH  32
#define NP     16        // patches per side
#define L      256       // patches per image
#define NCH    128       // descriptor channels
#define PLANE  (W512 * W512)

__device__ __forceinline__ unsigned short f2bf(float f) {
    __hip_bfloat16 h = __float2bfloat16(f);
    return *reinterpret_cast<unsigned short*>(&h);
}
__device__ __forceinline__ float bf2f(unsigned short u) {
    return __uint_as_float(((unsigned int)u) << 16);
}

// One block per (channel-group, strip). Phase A: strip softmax stats + att->LDS
// (det strip is 64 KiB, L2-resident across the 16 same-strip blocks that
// co-locate on one XCD via cg-in-high-bits). Phase B: stream 8 channel strips
// (contiguous 64 KiB each) against LDS att; normalize in epilogue.
__global__ __launch_bounds__(256)
void fused_kernel(const float* __restrict__ det,
                  const float* __restrict__ wsc,
                  const float* __restrict__ desc,
                  float* __restrict__ out) {
    __shared__ unsigned short att[PATCH][W512];  // unnormalized exp, bf16 (32 KiB)
    __shared__ float red[NP][2][4];              // per-patch partials {s,pu,pv,ps}

    const int bid   = blockIdx.x;    // cg*128 + strip -> same-strip blocks same XCD
    const int cg    = bid >> 7;      // channel group 0..15
    const int strip = bid & 127;     // b*16 + hp
    const int b     = strip >> 4;
    const int hp    = strip & 15;

    const int t    = threadIdx.x;
    const int wave = t >> 6;
    const int lane = t & 63;

    // ---------- Phase A: exp + per-patch {sum, u-, v-, w-moments} ----------
    const int c4  = t & 127;         // col-group: cols 4c4..4c4+3 (global col)
    const int h   = t >> 7;          // row half: rows h*16..h*16+15
    const int p   = c4 >> 3;         // patch within strip
    const int col = c4 * 4;
    const float u0 = (float)col, u1 = (float)(col + 1),
                u2 = (float)(col + 2), u3 = (float)(col + 3);

    const size_t sbase = (size_t)b * PLANE + (size_t)(hp * PATCH) * W512 + col;
    const float* dbase = det + sbase;
    const float* wbase = wsc + sbase;
    const bool   do_ws = (cg == 0);

    float s = 0.f, pu = 0.f, pv = 0.f, ps = 0.f;
    #pragma unroll
    for (int k = 0; k < 16; ++k) {
        const int r = h * 16 + k;
        const float4 d4 = *(const float4*)(dbase + (size_t)r * W512);
        const float e0 = expf(d4.x), e1 = expf(d4.y),
                    e2 = expf(d4.z), e3 = expf(d4.w);
        const float es = e0 + e1 + e2 + e3;
        s  += es;
        pu += e0 * u0 + e1 * u1 + e2 * u2 + e3 * u3;
        pv += es * (float)(hp * PATCH + r);
        if (do_ws) {
            const float4 w4 = *(const float4*)(wbase + (size_t)r * W512);
            ps += e0 * w4.x + e1 * w4.y + e2 * w4.z + e3 * w4.w;
        }
        ushort4 pk;
        pk.x = f2bf(e0); pk.y = f2bf(e1); pk.z = f2bf(e2); pk.w = f2bf(e3);
        *(ushort4*)&att[r][col] = pk;   // lane writes 8B at lane*8 -> 2-way, free
    }

    // 8-lane group reduce (group = one patch's columns for this row-half)
    #pragma unroll
    for (int o = 1; o <= 4; o <<= 1) {
        s  += __shfl_xor(s,  o, 64);
        pu += __shfl_xor(pu, o, 64);
        pv += __shfl_xor(pv, o, 64);
        ps += __shfl_xor(ps, o, 64);
    }
    if ((t & 7) == 0) {
        red[p][h][0] = s;  red[p][h][1] = pu;
        red[p][h][2] = pv; red[p][h][3] = ps;
    }
    __syncthreads();

    // coords + scores (f32 path, one block per strip does it)
    if (do_ws && t < NP) {
        const float ss  = red[t][0][0] + red[t][1][0];
        const float inv = 1.0f / ss;
        const int   blk = b * L + hp * NP + t;
        out[blk * 2 + 0]       = (red[t][0][1] + red[t][1][1]) * inv;
        out[blk * 2 + 1]       = (red[t][0][2] + red[t][1][2]) * inv;
        out[2 * (8 * L) + blk] = (red[t][0][3] + red[t][1][3]) * inv;
    }

    // ---------- Phase B: stream 8 channels against LDS att ----------
    const int wp0  = lane >> 3;
    const float inv0 = 1.0f / (red[wp0][0][0]     + red[wp0][1][0]);
    const float inv1 = 1.0f / (red[8 + wp0][0][0] + red[8 + wp0][1][0]);

    const int ch  = cg * 8 + wave * 2;
    const int lq4 = lane * 4;
    const float* dp0 = desc + (((size_t)(b * NCH + ch)) * W512 + hp * PATCH) * W512 + lq4;
    const float* dp1 = dp0 + PLANE;

    float a00 = 0.f, a01 = 0.f, a10 = 0.f, a11 = 0.f;
    #pragma unroll 4
    for (int r = 0; r < PATCH; ++r) {
        const int off = r * W512;
        const ushort4 uv0 = *(const ushort4*)&att[r][lq4];
        const ushort4 uv1 = *(const ushort4*)&att[r][256 + lq4];
        const float4 d00 = *(const float4*)(dp0 + off);
        const float4 d01 = *(const float4*)(dp0 + off + 256);
        const float4 d10 = *(const float4*)(dp1 + off);
        const float4 d11 = *(const float4*)(dp1 + off + 256);
        const float ax0 = bf2f(uv0.x), ay0 = bf2f(uv0.y),
                    az0 = bf2f(uv0.z), aw0 = bf2f(uv0.w);
        const float ax1 = bf2f(uv1.x), ay1 = bf2f(uv1.y),
                    az1 = bf2f(uv1.z), aw1 = bf2f(uv1.w);
        a00 += ax0 * d00.x + ay0 * d00.y + az0 * d00.z + aw0 * d00.w;
        a01 += ax1 * d01.x + ay1 * d01.y + az1 * d01.z + aw1 * d01.w;
        a10 += ax0 * d10.x + ay0 * d10.y + az0 * d10.z + aw0 * d10.w;
        a11 += ax1 * d11.x + ay1 * d11.y + az1 * d11.z + aw1 * d11.w;
    }

    #pragma unroll
    for (int o = 1; o <= 4; o <<= 1) {
        a00 += __shfl_xor(a00, o, 64);
        a01 += __shfl_xor(a01, o, 64);
        a10 += __shfl_xor(a10, o, 64);
        a11 += __shfl_xor(a11, o, 64);
    }

    if ((lane & 7) == 0) {
        float* outd = out + 4096 + 2048;
        float* o0 = outd + ((size_t)(b * NCH + ch)) * L + hp * NP;
        o0[wp0]     = a00 * inv0;
        o0[8 + wp0] = a01 * inv1;
        float* o1 = o0 + L;
        o1[wp0]     = a10 * inv0;
        o1[8 + wp0] = a11 * inv1;
    }
}

extern "C" void kernel_launch(void* const* d_in, const int* in_sizes, int n_in,
                              void* d_out, int out_size, void* d_ws, size_t ws_size,
                              hipStream_t stream) {
    const float* det  = (const float*)d_in[0];
    const float* wsc  = (const float*)d_in[1];
    const float* desc = (const float*)d_in[2];
    float* out = (float*)d_out;

    fused_kernel<<<dim3(2048), dim3(256), 0, stream>>>(det, wsc, desc, out);
}

// Round 4
// 171.458 us; speedup vs baseline: 1.1831x; 1.1831x over previous
//
#include <hip/hip_runtime.h>
#include <hip/hip_bf16.h>

#define W512   512
#define PATCH  32
#define NP     16        // patches per side
#define L      256       // patches per image
#define NCH    128       // descriptor channels
#define PLANE  (W512 * W512)

typedef float  f32x4 __attribute__((ext_vector_type(4)));
typedef unsigned short u16x4 __attribute__((ext_vector_type(4)));

__device__ __forceinline__ unsigned short f2bf(float f) {
    __hip_bfloat16 h = __float2bfloat16(f);
    return *reinterpret_cast<unsigned short*>(&h);
}
__device__ __forceinline__ float bf2f(unsigned short u) {
    return __uint_as_float(((unsigned int)u) << 16);
}

__device__ __forceinline__ float wave_max(float v) {
    #pragma unroll
    for (int o = 32; o; o >>= 1) v = fmaxf(v, __shfl_xor(v, o, 64));
    return v;
}
__device__ __forceinline__ float wave_sum(float v) {
    #pragma unroll
    for (int o = 32; o; o >>= 1) v += __shfl_xor(v, o, 64);
    return v;
}

// ---------------- kernel 1: softmax att + coords + scores ----------------
__global__ __launch_bounds__(256)
void att_kernel(const float* __restrict__ det,
                const float* __restrict__ wsc,
                float* __restrict__ out,
                unsigned short* __restrict__ attws) {
    __shared__ float red[12];

    const int blk = blockIdx.x;       // b*L + l
    const int b   = blk >> 8;
    const int l   = blk & 255;
    const int hp  = l >> 4;
    const int wp  = l & 15;

    const int t    = threadIdx.x;
    const int wave = t >> 6;
    const int lane = t & 63;
    const int r    = t >> 3;          // row within patch
    const int q    = t & 7;           // float4 index within row

    const int row = hp * PATCH + r;
    const int col = wp * PATCH + q * 4;
    const size_t pix = (size_t)b * PLANE + (size_t)row * W512 + col;

    const f32x4 d4 = __builtin_nontemporal_load((const f32x4*)(det + pix));

    float m = fmaxf(fmaxf(d4.x, d4.y), fmaxf(d4.z, d4.w));
    m = wave_max(m);
    if (lane == 0) red[wave] = m;
    __syncthreads();
    m = fmaxf(fmaxf(red[0], red[1]), fmaxf(red[2], red[3]));

    float e0 = expf(d4.x - m);
    float e1 = expf(d4.y - m);
    float e2 = expf(d4.z - m);
    float e3 = expf(d4.w - m);

    float s = wave_sum(e0 + e1 + e2 + e3);
    if (lane == 0) red[4 + wave] = s;
    __syncthreads();
    s = red[4] + red[5] + red[6] + red[7];
    const float inv = 1.0f / s;
    e0 *= inv; e1 *= inv; e2 *= inv; e3 *= inv;

    // normalized attention, bf16, image layout (same indexing as det)
    u16x4 pk;
    pk.x = f2bf(e0); pk.y = f2bf(e1); pk.z = f2bf(e2); pk.w = f2bf(e3);
    *(u16x4*)(attws + pix) = pk;

    const f32x4 w4 = __builtin_nontemporal_load((const f32x4*)(wsc + pix));
    float pu = e0 * (float)(col)     + e1 * (float)(col + 1)
             + e2 * (float)(col + 2) + e3 * (float)(col + 3);
    float pv = (e0 + e1 + e2 + e3) * (float)row;
    float ps = e0 * w4.x + e1 * w4.y + e2 * w4.z + e3 * w4.w;

    pu = wave_sum(pu);
    pv = wave_sum(pv);
    ps = wave_sum(ps);
    __syncthreads();
    if (lane == 0) { red[wave] = pu; red[4 + wave] = pv; red[8 + wave] = ps; }
    __syncthreads();
    if (t == 0) {
        out[blk * 2 + 0]       = red[0] + red[1] + red[2]  + red[3];
        out[blk * 2 + 1]       = red[4] + red[5] + red[6]  + red[7];
        out[2 * (8 * L) + blk] = red[8] + red[9] + red[10] + red[11];
    }
}

// ---------------- kernel 2: strip-sequential descriptor pooling ----------------
// block = one (b, hp, channel-group-of-8); wave owns 2 channels and streams
// the strip's contiguous 64 KiB region of each plane (nt: zero reuse).
__global__ __launch_bounds__(256)
void pool_kernel(const float* __restrict__ desc,
                 const unsigned short* __restrict__ attws,
                 float* __restrict__ outd) {
    const int bid   = blockIdx.x;     // cg in high bits -> same-strip blocks
    const int cg    = bid >> 7;       //   co-locate per XCD (bid%8)
    const int strip = bid & 127;      // b*16 + hp
    const int b     = strip >> 4;
    const int hp    = strip & 15;

    const int t    = threadIdx.x;
    const int wave = t >> 6;
    const int lane = t & 63;
    const int ch   = cg * 8 + wave * 2;

    const unsigned short* ap = attws + ((size_t)b * W512 + hp * PATCH) * W512 + lane * 4;
    const float* dp0 = desc + (((size_t)(b * NCH + ch)) * W512 + hp * PATCH) * W512 + lane * 4;
    const float* dp1 = dp0 + PLANE;

    float a00 = 0.f, a01 = 0.f, a10 = 0.f, a11 = 0.f;
    #pragma unroll 4
    for (int r = 0; r < PATCH; ++r) {
        const int off = r * W512;
        const u16x4 uv0 = *(const u16x4*)(ap + off);
        const u16x4 uv1 = *(const u16x4*)(ap + off + 256);
        const f32x4 d00 = __builtin_nontemporal_load((const f32x4*)(dp0 + off));
        const f32x4 d01 = __builtin_nontemporal_load((const f32x4*)(dp0 + off + 256));
        const f32x4 d10 = __builtin_nontemporal_load((const f32x4*)(dp1 + off));
        const f32x4 d11 = __builtin_nontemporal_load((const f32x4*)(dp1 + off + 256));
        const float ax0 = bf2f(uv0.x), ay0 = bf2f(uv0.y),
                    az0 = bf2f(uv0.z), aw0 = bf2f(uv0.w);
        const float ax1 = bf2f(uv1.x), ay1 = bf2f(uv1.y),
                    az1 = bf2f(uv1.z), aw1 = bf2f(uv1.w);
        a00 += ax0 * d00.x + ay0 * d00.y + az0 * d00.z + aw0 * d00.w;
        a01 += ax1 * d01.x + ay1 * d01.y + az1 * d01.z + aw1 * d01.w;
        a10 += ax0 * d10.x + ay0 * d10.y + az0 * d10.z + aw0 * d10.w;
        a11 += ax1 * d11.x + ay1 * d11.y + az1 * d11.z + aw1 * d11.w;
    }

    #pragma unroll
    for (int o = 1; o <= 4; o <<= 1) {
        a00 += __shfl_xor(a00, o, 64);
        a01 += __shfl_xor(a01, o, 64);
        a10 += __shfl_xor(a10, o, 64);
        a11 += __shfl_xor(a11, o, 64);
    }

    if ((lane & 7) == 0) {
        const int wp0 = lane >> 3;
        float* o0 = outd + ((size_t)(b * NCH + ch)) * L + hp * NP;
        o0[wp0]     = a00;
        o0[8 + wp0] = a01;
        float* o1 = o0 + L;
        o1[wp0]     = a10;
        o1[8 + wp0] = a11;
    }
}

extern "C" void kernel_launch(void* const* d_in, const int* in_sizes, int n_in,
                              void* d_out, int out_size, void* d_ws, size_t ws_size,
                              hipStream_t stream) {
    const float* det  = (const float*)d_in[0];
    const float* wsc  = (const float*)d_in[1];
    const float* desc = (const float*)d_in[2];
    float* out = (float*)d_out;
    unsigned short* attws = (unsigned short*)d_ws;   // 4 MiB bf16 attention map

    att_kernel<<<dim3(8 * L), dim3(256), 0, stream>>>(det, wsc, out, attws);
    pool_kernel<<<dim3(2048), dim3(256), 0, stream>>>(desc, attws, out + 4096 + 2048);
}